// Round 1
// baseline (912.908 us; speedup 1.0000x reference)
//
#include <hip/hip_runtime.h>

#define BB 64
#define PP 10000
#define EE 128
#define CC 100
#define S1 16            // scatter chunks per batch
#define CHUNK1 (PP / S1) // 625
#define S3 16            // gather chunks per batch
#define CHUNK3 (PP / S3) // 625

// ---------------------------------------------------------------------------
// Kernel 1: per-batch segment-sum into LDS-private accumulators, then merge
// to global (d_out cluster_embs region doubles as the sums accumulator).
// ---------------------------------------------------------------------------
__global__ __launch_bounds__(256) void scatter_kernel(
    const float* __restrict__ nodes, const int* __restrict__ ids,
    float* __restrict__ sums, float* __restrict__ cnts)
{
    __shared__ float s_sum[CC * EE];   // 51200 B
    __shared__ float s_cnt[CC];

    const int tid = threadIdx.x;
    for (int i = tid; i < CC * EE; i += 256) s_sum[i] = 0.f;
    if (tid < CC) s_cnt[tid] = 0.f;
    __syncthreads();

    const int b     = blockIdx.x / S1;
    const int chunk = blockIdx.x % S1;
    const int p0    = chunk * CHUNK1;
    const int lane  = tid & 31;   // 32 lanes x float4 = 128 floats per node row
    const int sub   = tid >> 5;   // 8 node rows in flight per block iteration

    const float4* src = (const float4*)(nodes + (size_t)b * PP * EE);
    const int*    idb = ids + b * PP;

    for (int p = p0 + sub; p < p0 + CHUNK1; p += 8) {
        int c = idb[p];
        float4 v = src[(size_t)p * (EE / 4) + lane];
        if ((unsigned)c < CC) {  // safety guard; ids are in [0,100)
            float* dst = &s_sum[c * EE + lane * 4];
            atomicAdd(dst + 0, v.x);
            atomicAdd(dst + 1, v.y);
            atomicAdd(dst + 2, v.z);
            atomicAdd(dst + 3, v.w);
            if (lane == 0) atomicAdd(&s_cnt[c], 1.0f);
        }
    }
    __syncthreads();

    float* gs = sums + (size_t)b * CC * EE;
    for (int i = tid; i < CC * EE; i += 256) atomicAdd(&gs[i], s_sum[i]);
    float* gc = cnts + b * CC;
    for (int i = tid; i < CC; i += 256) atomicAdd(&gc[i], s_cnt[i]);
}

// ---------------------------------------------------------------------------
// Kernel 2: mean + Linear(E,E), in-place on the sums region.
// out[row][e] = bias[e] + sum_k (sums[row][k]/max(cnt,1)) * W[e][k]
// W^T staged in LDS stride-129 (conflict-free stage & read); means staged
// transposed [k][8] so a wave-uniform float4 broadcast serves 4 rows at once.
// Each block: 16 rows = 2 iterations x (2 subs x 4 rows/thread).
// ---------------------------------------------------------------------------
__global__ __launch_bounds__(256) void project_kernel(
    float* __restrict__ ce,          // [6400][128] in: sums, out: projected
    const float* __restrict__ cnts,  // [6400]
    const float* __restrict__ W,     // [128][128] row-major W[e][k]
    const float* __restrict__ bias)  // [128]
{
    __shared__ float s_wt[EE * 129];   // s_wt[k*129 + e] = W[e][k]  (66048 B)
    __shared__ float s_mt[EE * 8];     // s_mt[k*8 + rr] = mean[row rr][k]

    const int tid = threadIdx.x;
    for (int i = tid; i < EE * EE; i += 256) {
        int e = i >> 7, k = i & 127;
        s_wt[k * 129 + e] = W[i];
    }

    const int e   = tid & 127;
    const int sub = tid >> 7;          // 0..1, wave-uniform
    const float be = bias[e];
    const int row0 = blockIdx.x * 16;

    for (int j = 0; j < 2; ++j) {
        __syncthreads();  // s_wt ready (j=0) / previous compute done (j=1)
        // stage 8 rows of means, transposed
        for (int i = tid; i < 8 * EE; i += 256) {
            int ee = i >> 3, rr = i & 7;
            int row = row0 + j * 8 + rr;
            float inv = 1.0f / fmaxf(cnts[row], 1.0f);
            s_mt[ee * 8 + rr] = ce[(size_t)row * EE + ee] * inv;
        }
        __syncthreads();

        float acc0 = be, acc1 = be, acc2 = be, acc3 = be;
        const float* wp = &s_wt[e];
        const float4* mp = (const float4*)s_mt;  // mp[k*2 + sub] = m[4sub..4sub+3][k]
#pragma unroll 8
        for (int k = 0; k < 128; ++k) {
            float  w = wp[k * 129];
            float4 m = mp[k * 2 + sub];
            acc0 = fmaf(w, m.x, acc0);
            acc1 = fmaf(w, m.y, acc1);
            acc2 = fmaf(w, m.z, acc2);
            acc3 = fmaf(w, m.w, acc3);
        }
        const int rbase = row0 + j * 8 + sub * 4;
        ce[(size_t)(rbase + 0) * EE + e] = acc0;
        ce[(size_t)(rbase + 1) * EE + e] = acc1;
        ce[(size_t)(rbase + 2) * EE + e] = acc2;
        ce[(size_t)(rbase + 3) * EE + e] = acc3;
    }
}

// ---------------------------------------------------------------------------
// Kernel 3: gather projected cluster embeddings back per node.
// Stage the batch's full [C][E] table (50 KB) in LDS once per block.
// ---------------------------------------------------------------------------
__global__ __launch_bounds__(256) void gather_kernel(
    const int* __restrict__ ids, const float* __restrict__ ce,
    float* __restrict__ gn)
{
    __shared__ float s_ce[CC * EE];

    const int tid = threadIdx.x;
    const int b = blockIdx.y;
    const float* ceb = ce + (size_t)b * CC * EE;
    for (int i = tid; i < CC * EE; i += 256) s_ce[i] = ceb[i];
    __syncthreads();

    const int p0   = blockIdx.x * CHUNK3;
    const int lane = tid & 31;
    const int sub  = tid >> 5;
    const int* idb = ids + b * PP;
    float4* dst = (float4*)(gn + (size_t)b * PP * EE);

    for (int p = p0 + sub; p < p0 + CHUNK3; p += 8) {
        int c = idb[p];
        if ((unsigned)c >= CC) c = 0;  // safety (never taken)
        float4 v = ((const float4*)(&s_ce[c * EE]))[lane];
        dst[(size_t)p * (EE / 4) + lane] = v;
    }
}

extern "C" void kernel_launch(void* const* d_in, const int* in_sizes, int n_in,
                              void* d_out, int out_size, void* d_ws, size_t ws_size,
                              hipStream_t stream)
{
    const float* nodes = (const float*)d_in[0];
    const int*   ids   = (const int*)d_in[1];
    // d_in[2] = num_clusters (scalar, fixed at 100 — compile-time here)
    const float* W     = (const float*)d_in[3];
    const float* bias  = (const float*)d_in[4];

    float* out  = (float*)d_out;
    float* ce   = out;                               // [64][100][128]
    float* gn   = out + (size_t)BB * CC * EE;        // [64][10000][128]
    float* cnts = (float*)d_ws;                      // [64][100]

    // zero the accumulators (harness poisons d_out/d_ws with 0xAA)
    hipMemsetAsync(ce,   0, (size_t)BB * CC * EE * sizeof(float), stream);
    hipMemsetAsync(cnts, 0, (size_t)BB * CC * sizeof(float), stream);

    hipLaunchKernelGGL(scatter_kernel, dim3(BB * S1), dim3(256), 0, stream,
                       nodes, ids, ce, cnts);
    hipLaunchKernelGGL(project_kernel, dim3(BB * CC / 16), dim3(256), 0, stream,
                       ce, cnts, W, bias);
    hipLaunchKernelGGL(gather_kernel, dim3(S3, BB), dim3(256), 0, stream,
                       ids, ce, gn);
}